// Round 8
// baseline (377.623 us; speedup 1.0000x reference)
//
#include <hip/hip_runtime.h>
#include <stdint.h>

#define LN_EPS 1e-5f

// ---------- bf16 helpers (RNE, bit-level) ----------
static __device__ __forceinline__ unsigned short f2bf_bits(float f) {
  union { float f; unsigned u; } v; v.f = f;
  unsigned r = v.u + 0x7FFFu + ((v.u >> 16) & 1u);
  return (unsigned short)(r >> 16);
}
static __device__ __forceinline__ float bf2f(unsigned short h) {
  union { unsigned u; float f; } v; v.u = ((unsigned)h) << 16;
  return v.f;
}

typedef __bf16 bf16x8 __attribute__((ext_vector_type(8)));
typedef float floatx4 __attribute__((ext_vector_type(4)));

// ---------- async global->LDS, 16B per lane ----------
typedef __attribute__((address_space(1))) unsigned int* gas_ptr;
typedef __attribute__((address_space(3))) unsigned int* las_ptr;
static __device__ __forceinline__ void async_cp16(const void* g, void* l) {
  __builtin_amdgcn_global_load_lds((gas_ptr)g, (las_ptr)l, 16, 0, 0);
}

// =====================================================================================
// perm: per batch, stable partition visible-first. newrow[b*4096+n] = within-batch
// destination row; cnt[b] = #visible.
// =====================================================================================
__global__ __launch_bounds__(256) void perm_kernel(
    const int* __restrict__ mask, int* __restrict__ newrow, int* __restrict__ cnt) {
  const int b = blockIdx.x, t = threadIdx.x;
  const int base = b * 4096 + t * 16;
  int v[16]; int s = 0;
#pragma unroll
  for (int i = 0; i < 16; ++i) { v[i] = (mask[base + i] != 0); s += v[i]; }
  const int lane = t & 63, wv = t >> 6;
  int scan = s;
  for (int o = 1; o < 64; o <<= 1) { int x = __shfl_up(scan, o); if (lane >= o) scan += x; }
  __shared__ int wsum[4], woff[4], stotal;
  if (lane == 63) wsum[wv] = scan;
  __syncthreads();
  if (t == 0) { int a = 0; for (int k = 0; k < 4; ++k) { woff[k] = a; a += wsum[k]; } stotal = a; cnt[b] = a; }
  __syncthreads();
  const int excl = scan - s + woff[wv];
  const int total = stotal;
  int run = 0;
#pragma unroll
  for (int i = 0; i < 16; ++i) {
    const int pos = t * 16 + i;
    const int visBefore = excl + run;
    newrow[b * 4096 + pos] = v[i] ? visBefore : total + (pos - visBefore);
    run += v[i];
  }
}

// =====================================================================================
// K_b: conv1 + LayerNorm(128) + mask + relu -> h2 bf16, compacted scatter.
// blocks >= 32768: fused fp32->bf16 weight conversion.
// =====================================================================================
__global__ __launch_bounds__(256) void conv1_ln_kernel(
    const float* __restrict__ points, const int* __restrict__ mask,
    const float* __restrict__ w1, const float* __restrict__ g1,
    const float* __restrict__ be1, unsigned short* __restrict__ h2,
    const int* __restrict__ newrow, const int* __restrict__ cnt,
    const float* __restrict__ w2, const float* __restrict__ w3,
    const float* __restrict__ w4, unsigned short* __restrict__ w2b,
    unsigned short* __restrict__ w3Rb, unsigned short* __restrict__ w4b) {
  if (blockIdx.x >= 32768) {
    int idx = (blockIdx.x - 32768) * 256 + threadIdx.x;
    if (idx < 32768) {
      w2b[idx] = f2bf_bits(w2[idx]);
    } else if (idx < 32768 + 131072) {
      int t = idx - 32768;
      int p = t >> 8, k = t & 255;
      w3Rb[t] = f2bf_bits(w3[p * 512 + 256 + k]);   // w3[:, 256:512]
    } else {
      int t = idx - 163840;
      w4b[t] = f2bf_bits(w4[t]);
    }
    return;
  }
  const int lane = threadIdx.x & 63;
  const int wv = threadIdx.x >> 6;
  const size_t p = (size_t)blockIdx.x * 4 + wv;
  const int dest = newrow[p];
  const int ceilv = (cnt[p >> 12] + 127) & ~127;
  if (dest >= ceilv) return;                 // row never read downstream
  const float x0 = points[p * 3 + 0];
  const float x1 = points[p * 3 + 1];
  const float x2 = points[p * 3 + 2];
  const int c0 = lane * 2, c1 = c0 + 1;
  float h00 = w1[c0 * 3] * x0 + w1[c0 * 3 + 1] * x1 + w1[c0 * 3 + 2] * x2;
  float h01 = w1[c1 * 3] * x0 + w1[c1 * 3 + 1] * x1 + w1[c1 * 3 + 2] * x2;
  float s = h00 + h01;
  for (int o = 32; o; o >>= 1) s += __shfl_xor(s, o);
  const float mu = s * (1.f / 128.f);
  const float d0 = h00 - mu, d1 = h01 - mu;
  float q = d0 * d0 + d1 * d1;
  for (int o = 32; o; o >>= 1) q += __shfl_xor(q, o);
  const float rs = rsqrtf(q * (1.f / 128.f) + LN_EPS);
  const bool vis = (mask[p] != 0);
  const float y0 = vis ? fmaxf(d0 * rs * g1[c0] + be1[c0], 0.f) : 0.f;
  const float y1 = vis ? fmaxf(d1 * rs * g1[c1] + be1[c1], 0.f) : 0.f;
  union { unsigned u; unsigned short s2[2]; } pk;
  pk.s2[0] = f2bf_bits(y0);
  pk.s2[1] = f2bf_bits(y1);
  const size_t prow = (p & ~(size_t)4095) + (size_t)dest;
  ((unsigned*)h2)[prow * 64 + lane] = pk.u;
}

// =====================================================================================
// GEMM2: h3 = h2 @ w2^T + b2 (bf16), 128x128 tile, BK=64 twin panels, A+B in LDS.
// Fused per-row-block colmax -> pg. Skip tiles (rb >= cnt): pg = b2 only.
// =====================================================================================
__global__ __launch_bounds__(256) void gemm2_kernel(
    const unsigned short* __restrict__ A, const unsigned short* __restrict__ Bw,
    unsigned short* __restrict__ outp, float* __restrict__ outp2,
    const float* __restrict__ extra, const int* __restrict__ cnt,
    int M, int N, int K) {
  __shared__ __align__(16) char smA[2][128 * 64];
  __shared__ __align__(16) char smB[2][128 * 64];
  __shared__ float lmax[2][128];

  const int tid = threadIdx.x;
  const int lane = tid & 63;
  const int w = tid >> 6;
  const int wm = w >> 1, wn = w & 1;

  const int NCT = 2;
  const int gid = blockIdx.x;
  const int xcd = gid & 7;
  const int slot = gid >> 3;
  const int rowsPerXcd = (M >> 7) >> 3;
  const int rowTile = xcd * rowsPerXcd + slot / NCT;
  const int colTile = slot % NCT;
  const size_t rowBase = (size_t)rowTile * 128;
  const int colBase = colTile * 128;

  const int cntb = cnt[rowBase >> 12];
  const int rb = (int)(rowBase & 4095);
  if (rb >= cntb) {
    if (tid < 128) outp2[(size_t)rowTile * N + colBase + tid] = extra[colBase + tid];
    return;
  }

  floatx4 acc[4][4];
  const floatx4 zero = {0.f, 0.f, 0.f, 0.f};
#pragma unroll
  for (int i = 0; i < 4; ++i)
#pragma unroll
    for (int j = 0; j < 4; ++j) acc[i][j] = zero;

  const int rSub = lane >> 2;
  const int cb16 = (lane & 3) * 16;
  const size_t Kb = (size_t)K * 2;
  const char* gA = (const char*)A + (rowBase + (size_t)(w * 32 + rSub)) * Kb + cb16;
  const char* gB = (const char*)Bw + ((size_t)colBase + (size_t)(w * 32 + rSub)) * Kb + cb16;
  char* lA0 = smA[0] + w * 2048;
  char* lA1 = smA[1] + w * 2048;
  char* lB0 = smB[0] + w * 2048;
  char* lB1 = smB[1] + w * 2048;
  const size_t skip16 = 16 * Kb;

  const int fm = lane & 15, fq = lane >> 4;
  const int fOff = fm * 64 + fq * 16;
  const char* pa0 = smA[0] + wm * 64 * 64 + fOff;
  const char* pa1 = smA[1] + wm * 64 * 64 + fOff;
  const char* pb0 = smB[0] + wn * 64 * 64 + fOff;
  const char* pb1 = smB[1] + wn * 64 * 64 + fOff;

  for (int k0 = 0; k0 < K; k0 += 64) {
    async_cp16(gA, lA0);
    async_cp16(gA + skip16, lA0 + 1024);
    async_cp16(gA + 64, lA1);
    async_cp16(gA + 64 + skip16, lA1 + 1024);
    async_cp16(gB, lB0);
    async_cp16(gB + skip16, lB0 + 1024);
    async_cp16(gB + 64, lB1);
    async_cp16(gB + 64 + skip16, lB1 + 1024);
    gA += 128; gB += 128;
    __syncthreads();
    bf16x8 af0[4], bg0[4], af1[4], bg1[4];
#pragma unroll
    for (int i = 0; i < 4; ++i) af0[i] = *(const bf16x8*)(pa0 + i * 16 * 64);
#pragma unroll
    for (int j = 0; j < 4; ++j) bg0[j] = *(const bf16x8*)(pb0 + j * 16 * 64);
#pragma unroll
    for (int i = 0; i < 4; ++i)
#pragma unroll
      for (int j = 0; j < 4; ++j)
        acc[i][j] = __builtin_amdgcn_mfma_f32_16x16x32_bf16(af0[i], bg0[j], acc[i][j], 0, 0, 0);
#pragma unroll
    for (int i = 0; i < 4; ++i) af1[i] = *(const bf16x8*)(pa1 + i * 16 * 64);
#pragma unroll
    for (int j = 0; j < 4; ++j) bg1[j] = *(const bf16x8*)(pb1 + j * 16 * 64);
#pragma unroll
    for (int i = 0; i < 4; ++i)
#pragma unroll
      for (int j = 0; j < 4; ++j)
        acc[i][j] = __builtin_amdgcn_mfma_f32_16x16x32_bf16(af1[i], bg1[j], acc[i][j], 0, 0, 0);
    __syncthreads();
  }

  float m4[4] = {-1e30f, -1e30f, -1e30f, -1e30f};
#pragma unroll
  for (int j = 0; j < 4; ++j) {
    const int col = colBase + wn * 64 + j * 16 + fm;
    const float ex = extra[col];
#pragma unroll
    for (int i = 0; i < 4; ++i) {
      const size_t row0 = rowBase + wm * 64 + i * 16 + fq * 4;
#pragma unroll
      for (int r = 0; r < 4; ++r) {
        const float v = acc[i][j][r] + ex;
        m4[j] = fmaxf(m4[j], v);
        outp[(row0 + r) * (size_t)N + col] = f2bf_bits(v);
      }
    }
  }
#pragma unroll
  for (int j = 0; j < 4; ++j) {
    m4[j] = fmaxf(m4[j], __shfl_xor(m4[j], 16));
    m4[j] = fmaxf(m4[j], __shfl_xor(m4[j], 32));
  }
  const float sel = (fq == 0) ? m4[0] : (fq == 1) ? m4[1] : (fq == 2) ? m4[2] : m4[3];
  lmax[wm][wn * 64 + fq * 16 + fm] = sel;
  __syncthreads();
  if (tid < 128) {
    const float v = fmaxf(lmax[0][tid], lmax[1][tid]);
    outp2[(size_t)rowTile * N + colBase + tid] = v;
  }
}

// =====================================================================================
// Fused gmax reduce + cvec (per batch): gm = max over 32 pg partials; cvec = w3L @ gm
// =====================================================================================
__global__ __launch_bounds__(256) void gmax_cvec_kernel(
    const float* __restrict__ pg, const float* __restrict__ w3,
    float* __restrict__ cvec) {
  __shared__ float gm[256];
  const int b = blockIdx.x, t = threadIdx.x;
  float m = -1e30f;
  for (int s = 0; s < 32; ++s) m = fmaxf(m, pg[((size_t)b * 32 + s) * 256 + t]);
  gm[t] = m;
  __syncthreads();
#pragma unroll
  for (int half = 0; half < 2; ++half) {
    const int p = half * 256 + t;
    const float* wr = w3 + (size_t)p * 512;
    float s = 0.f;
    for (int c = 0; c < 256; ++c) s += wr[c] * gm[c];
    cvec[b * 512 + p] = s;
  }
}

// =====================================================================================
// GEMM3 + LN2 + relu fused: h6 = relu(LN(h3 @ w3R^T + cvec[b])) -> h46 bf16.
// Tile 32 rows x 512 cols (FULL width -> row-wise LN in-block). BK=64 twin panels.
// A (32xBK) staged in 4 KB LDS; B (w3R, 256 KB, L2-hot) loaded DIRECT as fragments.
// Wave w owns cols [w*128, w*128+128); acc[2][8] (64 AGPRs).
// Skip: rb >= ceil128(cnt) -> return; rb in [cnt, ceil128) -> zero-fill 32 rows.
// Straddle rows (>= cnt) inside working block -> forced 0 (masked points).
// =====================================================================================
__global__ __launch_bounds__(256) void gemm3_ln_kernel(
    const unsigned short* __restrict__ A, const unsigned short* __restrict__ Bw,
    unsigned short* __restrict__ outp, const float* __restrict__ cvec,
    const int* __restrict__ cnt, const float* __restrict__ g2,
    const float* __restrict__ be2) {
  __shared__ __align__(16) char smA[2][32 * 64];   // 2 KB per panel
  __shared__ float sSum[4][32], sSq[4][32], sMu[32], sRs[32];

  const int tid = threadIdx.x;
  const int lane = tid & 63;
  const int w = tid >> 6;

  // XCD swizzle, NCT=1: M/32 = 4096 row tiles, 512 per XCD band
  const int gid = blockIdx.x;
  const int rowTile = (gid & 7) * 512 + (gid >> 3);
  const size_t rowBase = (size_t)rowTile * 32;
  const int batch = (int)(rowBase >> 12);
  const int rb = (int)(rowBase & 4095);
  const int cntb = cnt[batch];
  const int ceil128 = (cntb + 127) & ~127;
  if (rb >= ceil128) return;
  if (rb >= cntb) {     // fully masked rows inside GEMM4's straddle tile -> zeros
    uint4 z = {0, 0, 0, 0};
    uint4* O = (uint4*)(outp + rowBase * 512);
    for (int t = tid; t < 2048; t += 256) O[t] = z;   // 32*512*2B = 32 KB
    return;
  }

  floatx4 acc[2][8];
  const floatx4 zero = {0.f, 0.f, 0.f, 0.f};
#pragma unroll
  for (int i = 0; i < 2; ++i)
#pragma unroll
    for (int j = 0; j < 8; ++j) acc[i][j] = zero;

  // A staging: wave w -> panel (w>>1), row half (w&1); 1 cp16/wave/iter
  const int rSub = lane >> 2;
  const int cb16 = (lane & 3) * 16;
  const int p_st = w >> 1, h_st = w & 1;
  const char* gA = (const char*)A + (rowBase + (size_t)(h_st * 16 + rSub)) * 512 + p_st * 64 + cb16;
  char* lA = smA[p_st] + h_st * 1024;

  // B direct: col n = w*128 + j*16 + fm, row-major stride 512 B (K=256 bf16)
  const int fm = lane & 15, fq = lane >> 4;
  const char* pB = (const char*)Bw + (size_t)(w * 128 + fm) * 512 + fq * 16;

  const char* pa0 = smA[0] + fm * 64 + fq * 16;
  const char* pa1 = smA[1] + fm * 64 + fq * 16;

  int koff = 0;
  for (int it = 0; it < 4; ++it) {      // K=256, BK=64
    async_cp16(gA, lA);
    gA += 128;
    bf16x8 bg0[8], bg1[8];
#pragma unroll
    for (int j = 0; j < 8; ++j) bg0[j] = *(const bf16x8*)(pB + j * 8192 + koff);
#pragma unroll
    for (int j = 0; j < 8; ++j) bg1[j] = *(const bf16x8*)(pB + j * 8192 + koff + 64);
    __syncthreads();
    bf16x8 af0[2], af1[2];
#pragma unroll
    for (int i = 0; i < 2; ++i) af0[i] = *(const bf16x8*)(pa0 + i * 16 * 64);
#pragma unroll
    for (int i = 0; i < 2; ++i) af1[i] = *(const bf16x8*)(pa1 + i * 16 * 64);
#pragma unroll
    for (int i = 0; i < 2; ++i)
#pragma unroll
      for (int j = 0; j < 8; ++j)
        acc[i][j] = __builtin_amdgcn_mfma_f32_16x16x32_bf16(af0[i], bg0[j], acc[i][j], 0, 0, 0);
#pragma unroll
    for (int i = 0; i < 2; ++i)
#pragma unroll
      for (int j = 0; j < 8; ++j)
        acc[i][j] = __builtin_amdgcn_mfma_f32_16x16x32_bf16(af1[i], bg1[j], acc[i][j], 0, 0, 0);
    koff += 128;
    __syncthreads();
  }

  // add cvec, per-row stats
  float ex[8];
#pragma unroll
  for (int j = 0; j < 8; ++j) ex[j] = cvec[batch * 512 + w * 128 + j * 16 + fm];
  float sS[2][4], sQ[2][4];
#pragma unroll
  for (int i = 0; i < 2; ++i)
#pragma unroll
    for (int r = 0; r < 4; ++r) {
      float s = 0.f, q = 0.f;
#pragma unroll
      for (int j = 0; j < 8; ++j) {
        const float v = acc[i][j][r] + ex[j];
        acc[i][j][r] = v;
        s += v; q += v * v;
      }
#pragma unroll
      for (int off = 1; off < 16; off <<= 1) {
        s += __shfl_xor(s, off);
        q += __shfl_xor(q, off);
      }
      sS[i][r] = s; sQ[i][r] = q;
    }
  if (fm == 0) {
#pragma unroll
    for (int i = 0; i < 2; ++i)
#pragma unroll
      for (int r = 0; r < 4; ++r) {
        const int row = i * 16 + fq * 4 + r;
        sSum[w][row] = sS[i][r];
        sSq[w][row] = sQ[i][r];
      }
  }
  __syncthreads();
  if (tid < 32) {
    const float S = sSum[0][tid] + sSum[1][tid] + sSum[2][tid] + sSum[3][tid];
    const float Q = sSq[0][tid] + sSq[1][tid] + sSq[2][tid] + sSq[3][tid];
    const float mu = S * (1.f / 512.f);
    sMu[tid] = mu;
    sRs[tid] = rsqrtf(Q * (1.f / 512.f) - mu * mu + LN_EPS);
  }
  __syncthreads();

  float gj[8], bj[8];
#pragma unroll
  for (int j = 0; j < 8; ++j) {
    const int col = w * 128 + j * 16 + fm;
    gj[j] = g2[col]; bj[j] = be2[col];
  }
#pragma unroll
  for (int i = 0; i < 2; ++i)
#pragma unroll
    for (int r = 0; r < 4; ++r) {
      const int row = i * 16 + fq * 4 + r;
      const float mu = sMu[row], rs = sRs[row];
      const bool live = (rb + row) < cntb;
#pragma unroll
      for (int j = 0; j < 8; ++j) {
        const int col = w * 128 + j * 16 + fm;
        float y = live ? fmaxf((acc[i][j][r] - mu) * rs * gj[j] + bj[j], 0.f) : 0.f;
        outp[(rowBase + row) * 512 + col] = f2bf_bits(y);
      }
    }
}

// =====================================================================================
// GEMM4 (B-direct): colmax over 128 rows of h6 @ w4^T -> pmax. 128x128 tile, BK=64.
// A staged via cp16 (twin 8 KB panels); B fragments loaded directly from L1/L2.
// =====================================================================================
__global__ __launch_bounds__(256) void gemm4_kernel(
    const unsigned short* __restrict__ A, const unsigned short* __restrict__ Bw,
    float* __restrict__ outp2, const int* __restrict__ cnt, int M, int N, int K) {
  __shared__ __align__(16) char smA[2][128 * 64];   // two 8 KB panels
  __shared__ float lmax[2][128];

  const int tid = threadIdx.x;
  const int lane = tid & 63;
  const int w = tid >> 6;
  const int wm = w >> 1, wn = w & 1;

  const int NCT = 8;
  const int gid = blockIdx.x;
  const int xcd = gid & 7;
  const int slot = gid >> 3;
  const int rowsPerXcd = (M >> 7) >> 3;
  const int rowTile = xcd * rowsPerXcd + slot / NCT;
  const int colTile = slot % NCT;
  const size_t rowBase = (size_t)rowTile * 128;
  const int colBase = colTile * 128;

  const int cntb = cnt[rowBase >> 12];
  const int rb = (int)(rowBase & 4095);
  if (rb >= cntb) {
    if (tid < 128) outp2[(size_t)rowTile * N + colBase + tid] = 0.f;
    return;
  }

  floatx4 acc[4][4];
  const floatx4 zero = {0.f, 0.f, 0.f, 0.f};
#pragma unroll
  for (int i = 0; i < 4; ++i)
#pragma unroll
    for (int j = 0; j < 4; ++j) acc[i][j] = zero;

  const int rSub = lane >> 2;
  const int cb16 = (lane & 3) * 16;
  const size_t Kb = (size_t)K * 2;    // 1024
  const char* gA = (const char*)A + (rowBase + (size_t)(w * 32 + rSub)) * Kb + cb16;
  char* lA0 = smA[0] + w * 2048;
  char* lA1 = smA[1] + w * 2048;
  const size_t skip16 = 16 * Kb;

  const int fm = lane & 15, fq = lane >> 4;
  const int fOff = fm * 64 + fq * 16;
  const char* pa0 = smA[0] + wm * 64 * 64 + fOff;
  const char* pa1 = smA[1] + wm * 64 * 64 + fOff;
  // B direct: col n = colBase + wn*64 + j*16 + fm, stride Kb
  const char* pB = (const char*)Bw + ((size_t)colBase + wn * 64 + fm) * Kb + fq * 16;

  size_t koff = 0;
  for (int k0 = 0; k0 < K; k0 += 64) {
    async_cp16(gA, lA0);
    async_cp16(gA + skip16, lA0 + 1024);
    async_cp16(gA + 64, lA1);
    async_cp16(gA + 64 + skip16, lA1 + 1024);
    gA += 128;
    bf16x8 bg0[4], bg1[4];
#pragma unroll
    for (int j = 0; j < 4; ++j) bg0[j] = *(const bf16x8*)(pB + (size_t)j * 16 * Kb + koff);
#pragma unroll
    for (int j = 0; j < 4; ++j) bg1[j] = *(const bf16x8*)(pB + (size_t)j * 16 * Kb + koff + 64);
    __syncthreads();
    bf16x8 af0[4], af1[4];
#pragma unroll
    for (int i = 0; i < 4; ++i) af0[i] = *(const bf16x8*)(pa0 + i * 16 * 64);
#pragma unroll
    for (int i = 0; i < 4; ++i) af1[i] = *(const bf16x8*)(pa1 + i * 16 * 64);
#pragma unroll
    for (int i = 0; i < 4; ++i)
#pragma unroll
      for (int j = 0; j < 4; ++j)
        acc[i][j] = __builtin_amdgcn_mfma_f32_16x16x32_bf16(af0[i], bg0[j], acc[i][j], 0, 0, 0);
#pragma unroll
    for (int i = 0; i < 4; ++i)
#pragma unroll
      for (int j = 0; j < 4; ++j)
        acc[i][j] = __builtin_amdgcn_mfma_f32_16x16x32_bf16(af1[i], bg1[j], acc[i][j], 0, 0, 0);
    koff += 128;
    __syncthreads();
  }

  float m4[4] = {-1e30f, -1e30f, -1e30f, -1e30f};
#pragma unroll
  for (int j = 0; j < 4; ++j) {
#pragma unroll
    for (int i = 0; i < 4; ++i)
#pragma unroll
      for (int r = 0; r < 4; ++r) m4[j] = fmaxf(m4[j], acc[i][j][r]);
    m4[j] = fmaxf(m4[j], __shfl_xor(m4[j], 16));
    m4[j] = fmaxf(m4[j], __shfl_xor(m4[j], 32));
  }
  const float sel = (fq == 0) ? m4[0] : (fq == 1) ? m4[1] : (fq == 2) ? m4[2] : m4[3];
  lmax[wm][wn * 64 + fq * 16 + fm] = sel;
  __syncthreads();
  if (tid < 128) {
    const float v = fmaxf(lmax[0][tid], lmax[1][tid]);
    outp2[(size_t)rowTile * N + colBase + tid] = v;
  }
}

// =====================================================================================
// K_j: out[b][f] = max over 32 row-blocks of pmax + b4[f]
// =====================================================================================
__global__ __launch_bounds__(256) void final_kernel(
    const float* __restrict__ pmax, const float* __restrict__ b4,
    float* __restrict__ out) {
  const int idx = blockIdx.x * 256 + threadIdx.x;
  const int b = idx >> 10, f = idx & 1023;
  float m = -1e30f;
  for (int r = 0; r < 32; ++r) m = fmaxf(m, pmax[((size_t)(b * 32 + r)) * 1024 + f]);
  out[idx] = m + b4[f];
}

// =====================================================================================
extern "C" void kernel_launch(void* const* d_in, const int* in_sizes, int n_in,
                              void* d_out, int out_size, void* d_ws, size_t ws_size,
                              hipStream_t stream) {
  const float* points = (const float*)d_in[0];
  const int* mask = (const int*)d_in[1];
  const float* w1 = (const float*)d_in[2];
  const float* g1 = (const float*)d_in[3];
  const float* be1 = (const float*)d_in[4];
  const float* w2 = (const float*)d_in[5];
  const float* b2 = (const float*)d_in[6];
  const float* w3 = (const float*)d_in[7];
  const float* g2 = (const float*)d_in[8];
  const float* be2 = (const float*)d_in[9];
  const float* w4 = (const float*)d_in[10];
  const float* b4 = (const float*)d_in[11];
  float* out = (float*)d_out;
  char* ws = (char*)d_ws;

  // workspace layout (h46 aliases h2: h2 is dead before gemm3_ln writes h46)
  const size_t OFF_H46 = 0;                         // 134217728 B (bf16 131072x512)
  const size_t OFF_H2 = 0;                          //  33554432 B (bf16 131072x128)
  const size_t OFF_H3 = 134217728;                  //  67108864 B (bf16 131072x256)
  const size_t OFF_W2B = OFF_H3 + 67108864;         //     65536 B
  const size_t OFF_W3RB = OFF_W2B + 65536;          //    262144 B
  const size_t OFF_W4B = OFF_W3RB + 262144;         //   1048576 B
  const size_t OFF_PG = OFF_W4B + 1048576;          //   1048576 B (pg: 1024x256 f32)
  const size_t OFF_CVEC = OFF_PG + 1048576;         //     65536 B
  const size_t OFF_PMAX = OFF_CVEC + 65536;         //   4194304 B
  const size_t OFF_CNT = OFF_PMAX + 4194304;        //      4096 B
  const size_t OFF_NEWROW = OFF_CNT + 4096;         //    524288 B

  unsigned short* h2 = (unsigned short*)(ws + OFF_H2);
  unsigned short* h3 = (unsigned short*)(ws + OFF_H3);
  unsigned short* h46 = (unsigned short*)(ws + OFF_H46);
  unsigned short* w2b = (unsigned short*)(ws + OFF_W2B);
  unsigned short* w3Rb = (unsigned short*)(ws + OFF_W3RB);
  unsigned short* w4b = (unsigned short*)(ws + OFF_W4B);
  float* pg = (float*)(ws + OFF_PG);
  float* cvecp = (float*)(ws + OFF_CVEC);
  float* pmaxp = (float*)(ws + OFF_PMAX);
  int* cntp = (int*)(ws + OFF_CNT);
  int* newrow = (int*)(ws + OFF_NEWROW);

  // 0. visible-first compaction map per batch
  perm_kernel<<<32, 256, 0, stream>>>(mask, newrow, cntp);
  // 1. conv1 + LN1 + mask + relu -> h2 (compacted); fused weight fp32->bf16
  conv1_ln_kernel<<<32768 + 2688, 256, 0, stream>>>(points, mask, w1, g1, be1, h2,
                                                    newrow, cntp, w2, w3, w4, w2b, w3Rb, w4b);
  // 2. h3 = h2 @ w2^T + b2, fused colmax -> pg
  gemm2_kernel<<<2048, 256, 0, stream>>>(h2, w2b, h3, pg, b2, cntp, 131072, 256, 128);
  // 3. gmax + cvec fused
  gmax_cvec_kernel<<<32, 256, 0, stream>>>(pg, w3, cvecp);
  // 4. h6 = relu(LN(h3 @ w3R^T + cvec)) -> h46  (LN2 fused, B-direct)
  gemm3_ln_kernel<<<4096, 256, 0, stream>>>(h3, w3Rb, h46, cvecp, cntp, g2, be2);
  // 5. h7 colmax -> pmax (B-direct GEMM)
  gemm4_kernel<<<8192, 256, 0, stream>>>(h46, w4b, pmaxp, cntp, 131072, 1024, 512);
  // 6. out = max over row-blocks + b4
  final_kernel<<<128, 256, 0, stream>>>(pmaxp, b4, out);
}

// Round 9
// 282.133 us; speedup vs baseline: 1.3385x; 1.3385x over previous
//
#include <hip/hip_runtime.h>
#include <stdint.h>

#define LN_EPS 1e-5f

// ---------- bf16 helpers (RNE, bit-level) ----------
static __device__ __forceinline__ unsigned short f2bf_bits(float f) {
  union { float f; unsigned u; } v; v.f = f;
  unsigned r = v.u + 0x7FFFu + ((v.u >> 16) & 1u);
  return (unsigned short)(r >> 16);
}
static __device__ __forceinline__ float bf2f(unsigned short h) {
  union { unsigned u; float f; } v; v.u = ((unsigned)h) << 16;
  return v.f;
}

typedef __bf16 bf16x8 __attribute__((ext_vector_type(8)));
typedef float floatx4 __attribute__((ext_vector_type(4)));

// ---------- async global->LDS, 16B per lane ----------
typedef __attribute__((address_space(1))) unsigned int* gas_ptr;
typedef __attribute__((address_space(3))) unsigned int* las_ptr;
static __device__ __forceinline__ void async_cp16(const void* g, void* l) {
  __builtin_amdgcn_global_load_lds((gas_ptr)g, (las_ptr)l, 16, 0, 0);
}

// =====================================================================================
// perm: per batch, stable partition visible-first. newrow[b*4096+n] = within-batch
// destination row; cnt[b] = #visible.
// =====================================================================================
__global__ __launch_bounds__(256) void perm_kernel(
    const int* __restrict__ mask, int* __restrict__ newrow, int* __restrict__ cnt) {
  const int b = blockIdx.x, t = threadIdx.x;
  const int base = b * 4096 + t * 16;
  int v[16]; int s = 0;
#pragma unroll
  for (int i = 0; i < 16; ++i) { v[i] = (mask[base + i] != 0); s += v[i]; }
  const int lane = t & 63, wv = t >> 6;
  int scan = s;
  for (int o = 1; o < 64; o <<= 1) { int x = __shfl_up(scan, o); if (lane >= o) scan += x; }
  __shared__ int wsum[4], woff[4], stotal;
  if (lane == 63) wsum[wv] = scan;
  __syncthreads();
  if (t == 0) { int a = 0; for (int k = 0; k < 4; ++k) { woff[k] = a; a += wsum[k]; } stotal = a; cnt[b] = a; }
  __syncthreads();
  const int excl = scan - s + woff[wv];
  const int total = stotal;
  int run = 0;
#pragma unroll
  for (int i = 0; i < 16; ++i) {
    const int pos = t * 16 + i;
    const int visBefore = excl + run;
    newrow[b * 4096 + pos] = v[i] ? visBefore : total + (pos - visBefore);
    run += v[i];
  }
}

// =====================================================================================
// K_b: conv1 (K=3, fp32 exact) + LayerNorm(128) + mask + relu -> h2 bf16, compacted
// scatter via newrow. visibility == (dest < cnt[b]) — no mask re-read.
// Rows >= ceil128(cnt) never read downstream -> not written.
// blocks >= 32768: fused fp32->bf16 weight conversion.
// =====================================================================================
__global__ __launch_bounds__(256) void conv1_ln_kernel(
    const float* __restrict__ points,
    const float* __restrict__ w1, const float* __restrict__ g1,
    const float* __restrict__ be1, unsigned short* __restrict__ h2,
    const int* __restrict__ newrow, const int* __restrict__ cnt,
    const float* __restrict__ w2, const float* __restrict__ w3,
    const float* __restrict__ w4, unsigned short* __restrict__ w2b,
    unsigned short* __restrict__ w3Rb, unsigned short* __restrict__ w4b) {
  if (blockIdx.x >= 32768) {
    int idx = (blockIdx.x - 32768) * 256 + threadIdx.x;
    if (idx < 32768) {
      w2b[idx] = f2bf_bits(w2[idx]);
    } else if (idx < 32768 + 131072) {
      int t = idx - 32768;
      int p = t >> 8, k = t & 255;
      w3Rb[t] = f2bf_bits(w3[p * 512 + 256 + k]);   // w3[:, 256:512]
    } else {
      int t = idx - 163840;
      w4b[t] = f2bf_bits(w4[t]);
    }
    return;
  }
  const int lane = threadIdx.x & 63;
  const int wv = threadIdx.x >> 6;
  const size_t p = (size_t)blockIdx.x * 4 + wv;
  const int dest = newrow[p];
  const int cntb = cnt[p >> 12];
  const int ceilv = (cntb + 127) & ~127;
  if (dest >= ceilv) return;                 // row never read downstream
  const bool vis = (dest < cntb);            // compaction: visible rows land in front
  const float x0 = points[p * 3 + 0];
  const float x1 = points[p * 3 + 1];
  const float x2 = points[p * 3 + 2];
  const int c0 = lane * 2, c1 = c0 + 1;
  float h00 = w1[c0 * 3] * x0 + w1[c0 * 3 + 1] * x1 + w1[c0 * 3 + 2] * x2;
  float h01 = w1[c1 * 3] * x0 + w1[c1 * 3 + 1] * x1 + w1[c1 * 3 + 2] * x2;
  float s = h00 + h01;
  for (int o = 32; o; o >>= 1) s += __shfl_xor(s, o);
  const float mu = s * (1.f / 128.f);
  const float d0 = h00 - mu, d1 = h01 - mu;
  float q = d0 * d0 + d1 * d1;
  for (int o = 32; o; o >>= 1) q += __shfl_xor(q, o);
  const float rs = rsqrtf(q * (1.f / 128.f) + LN_EPS);
  const float y0 = vis ? fmaxf(d0 * rs * g1[c0] + be1[c0], 0.f) : 0.f;
  const float y1 = vis ? fmaxf(d1 * rs * g1[c1] + be1[c1], 0.f) : 0.f;
  union { unsigned u; unsigned short s2[2]; } pk;
  pk.s2[0] = f2bf_bits(y0);
  pk.s2[1] = f2bf_bits(y1);
  const size_t prow = (p & ~(size_t)4095) + (size_t)dest;
  ((unsigned*)h2)[prow * 64 + lane] = pk.u;
}

// =====================================================================================
// MFMA GEMM: C[M,N] = A[M,K] * Bw[N,K]^T  (bf16 in, fp32 acc), 128x128 tile, BK=64
// (two 32-col panels, A AND B staged via cp16 -> LDS; B-direct was a 2x regression:
// per-wave B register loads demand ~310 B/cyc/CU from L2 vs ~56 available).
// XCD-aware swizzle (gid&7 band). Visible-first compaction skip paths.
// EPI 1: out bf16 = acc + extra[(row>>12)*N + col]; skip -> return (no readers)
// EPI 2: outp2[rowTile*N+col] = colmax(acc);         skip -> write 0
// EPI 3: out bf16 = acc + extra[col], colmax -> outp2; skip -> pg=b2 only
// =====================================================================================
template <int EPI, int NCT>
__global__ __launch_bounds__(256) void gemm_bt(
    const unsigned short* __restrict__ A, const unsigned short* __restrict__ Bw,
    void* __restrict__ outp, float* __restrict__ outp2,
    const float* __restrict__ extra, const int* __restrict__ cnt,
    int M, int N, int K) {
  __shared__ __align__(16) char smA[2][128 * 64];   // two 8 KB panels (k lo/hi)
  __shared__ __align__(16) char smB[2][128 * 64];
  __shared__ float lmax[2][128];

  const int tid = threadIdx.x;
  const int lane = tid & 63;
  const int w = tid >> 6;          // wave 0..3
  const int wm = w >> 1, wn = w & 1;

  // XCD-aware tile coordinates
  const int gid = blockIdx.x;
  const int xcd = gid & 7;
  const int slot = gid >> 3;
  const int rowsPerXcd = (M >> 7) >> 3;          // NRT / 8
  const int rowTile = xcd * rowsPerXcd + slot / NCT;
  const int colTile = slot % NCT;
  const size_t rowBase = (size_t)rowTile * 128;
  const int colBase = colTile * 128;

  // sparsity skip: rows [rowBase, rowBase+128) all zero-A when rb >= cnt[batch]
  const int cntb = cnt[rowBase >> 12];
  const int rb = (int)(rowBase & 4095);
  if (rb >= cntb) {
    if (EPI == 1) return;                              // no readers of these rows
    if (EPI == 2) {                                    // masked-row contribution = 0
      if (tid < 128) outp2[(size_t)rowTile * N + colBase + tid] = 0.f;
      return;
    }
    if (EPI == 3) {                                    // gmax contribution = b2
      if (tid < 128) outp2[(size_t)rowTile * N + colBase + tid] = extra[colBase + tid];
      return;
    }
  }

  floatx4 acc[4][4];
  const floatx4 zero = {0.f, 0.f, 0.f, 0.f};
#pragma unroll
  for (int i = 0; i < 4; ++i)
#pragma unroll
    for (int j = 0; j < 4; ++j) acc[i][j] = zero;

  // staging: wave w stages rows [w*32, w*32+32) of both tiles; per panel: 2 calls
  const int rSub = lane >> 2;            // 0..15
  const int cb16 = (lane & 3) * 16;      // byte within 64B row chunk
  const size_t Kb = (size_t)K * 2;
  const char* gA = (const char*)A + (rowBase + (size_t)(w * 32 + rSub)) * Kb + cb16;
  const char* gB = (const char*)Bw + ((size_t)colBase + (size_t)(w * 32 + rSub)) * Kb + cb16;
  char* lA0 = smA[0] + w * 2048;
  char* lA1 = smA[1] + w * 2048;
  char* lB0 = smB[0] + w * 2048;
  char* lB1 = smB[1] + w * 2048;
  const size_t skip16 = 16 * Kb;

  // fragment addressing
  const int fm = lane & 15, fq = lane >> 4;
  const int fOff = fm * 64 + fq * 16;
  const char* pa0 = smA[0] + wm * 64 * 64 + fOff;
  const char* pa1 = smA[1] + wm * 64 * 64 + fOff;
  const char* pb0 = smB[0] + wn * 64 * 64 + fOff;
  const char* pb1 = smB[1] + wn * 64 * 64 + fOff;

  for (int k0 = 0; k0 < K; k0 += 64) {
    async_cp16(gA, lA0);
    async_cp16(gA + skip16, lA0 + 1024);
    async_cp16(gA + 64, lA1);
    async_cp16(gA + 64 + skip16, lA1 + 1024);
    async_cp16(gB, lB0);
    async_cp16(gB + skip16, lB0 + 1024);
    async_cp16(gB + 64, lB1);
    async_cp16(gB + 64 + skip16, lB1 + 1024);
    gA += 128; gB += 128;                // advance 64 bf16
    __syncthreads();
    bf16x8 af0[4], bg0[4], af1[4], bg1[4];
#pragma unroll
    for (int i = 0; i < 4; ++i) af0[i] = *(const bf16x8*)(pa0 + i * 16 * 64);
#pragma unroll
    for (int j = 0; j < 4; ++j) bg0[j] = *(const bf16x8*)(pb0 + j * 16 * 64);
#pragma unroll
    for (int i = 0; i < 4; ++i)
#pragma unroll
      for (int j = 0; j < 4; ++j)
        acc[i][j] = __builtin_amdgcn_mfma_f32_16x16x32_bf16(af0[i], bg0[j], acc[i][j], 0, 0, 0);
#pragma unroll
    for (int i = 0; i < 4; ++i) af1[i] = *(const bf16x8*)(pa1 + i * 16 * 64);
#pragma unroll
    for (int j = 0; j < 4; ++j) bg1[j] = *(const bf16x8*)(pb1 + j * 16 * 64);
#pragma unroll
    for (int i = 0; i < 4; ++i)
#pragma unroll
      for (int j = 0; j < 4; ++j)
        acc[i][j] = __builtin_amdgcn_mfma_f32_16x16x32_bf16(af1[i], bg1[j], acc[i][j], 0, 0, 0);
    __syncthreads();
  }

  float m4[4] = {-1e30f, -1e30f, -1e30f, -1e30f};

  if (EPI == 1 || EPI == 3) {
    unsigned short* O = (unsigned short*)outp;
#pragma unroll
    for (int j = 0; j < 4; ++j) {
      const int col = colBase + wn * 64 + j * 16 + fm;
      const float ex = (EPI == 1) ? extra[(rowBase >> 12) * (size_t)N + col] : extra[col];
#pragma unroll
      for (int i = 0; i < 4; ++i) {
        const size_t row0 = rowBase + wm * 64 + i * 16 + fq * 4;
#pragma unroll
        for (int r = 0; r < 4; ++r) {
          const float v = acc[i][j][r] + ex;
          if (EPI == 3) m4[j] = fmaxf(m4[j], v);
          O[(row0 + r) * (size_t)N + col] = f2bf_bits(v);
        }
      }
    }
  } else {  // EPI == 2: pure column-max
#pragma unroll
    for (int j = 0; j < 4; ++j) {
#pragma unroll
      for (int i = 0; i < 4; ++i)
#pragma unroll
        for (int r = 0; r < 4; ++r) m4[j] = fmaxf(m4[j], acc[i][j][r]);
    }
  }

  if (EPI == 2 || EPI == 3) {
#pragma unroll
    for (int j = 0; j < 4; ++j) {
      m4[j] = fmaxf(m4[j], __shfl_xor(m4[j], 16));
      m4[j] = fmaxf(m4[j], __shfl_xor(m4[j], 32));
    }
    const float sel = (fq == 0) ? m4[0] : (fq == 1) ? m4[1] : (fq == 2) ? m4[2] : m4[3];
    lmax[wm][wn * 64 + fq * 16 + fm] = sel;
    __syncthreads();
    if (tid < 128) {
      const float v = fmaxf(lmax[0][tid], lmax[1][tid]);
      outp2[(size_t)rowTile * N + colBase + tid] = v;
    }
  }
}

// =====================================================================================
// Fused gmax reduce + cvec (per batch): gm = max over 32 pg partials; cvec = w3L @ gm
// =====================================================================================
__global__ __launch_bounds__(256) void gmax_cvec_kernel(
    const float* __restrict__ pg, const float* __restrict__ w3,
    float* __restrict__ cvec) {
  __shared__ float gm[256];
  const int b = blockIdx.x, t = threadIdx.x;
  float m = -1e30f;
  for (int s = 0; s < 32; ++s) m = fmaxf(m, pg[((size_t)b * 32 + s) * 256 + t]);
  gm[t] = m;
  __syncthreads();
#pragma unroll
  for (int half = 0; half < 2; ++half) {
    const int p = half * 256 + t;
    const float* wr = w3 + (size_t)p * 512;
    float s = 0.f;
    for (int c = 0; c < 256; ++c) s += wr[c] * gm[c];
    cvec[b * 512 + p] = s;
  }
}

// =====================================================================================
// K_h: LayerNorm(512) + relu in place on h46 (compacted). rows < cnt: LN+relu;
// rows in [cnt, ceil128(cnt)): zero (read by GEMM4 straddle tile);
// rows >= ceil128: untouched (no readers).
// =====================================================================================
__global__ __launch_bounds__(256) void ln2_kernel(
    unsigned short* __restrict__ h46, const int* __restrict__ cnt,
    const float* __restrict__ g2, const float* __restrict__ be2) {
  const int lane = threadIdx.x & 63;
  const int wv = threadIdx.x >> 6;
  const size_t p = (size_t)blockIdx.x * 4 + wv;
  const int cb = cnt[p >> 12];
  const int pin = (int)(p & 4095);
  const int ceilv = (cb + 127) & ~127;
  if (pin >= ceilv) return;
  unsigned short* row = h46 + p * 512;
  const int c0 = lane * 8;
  if (pin >= cb) {                            // straddle zero-fill
    const uint4 z = {0, 0, 0, 0};
    *(uint4*)(row + c0) = z;
    return;
  }
  union { uint4 v; unsigned short s[8]; } in;
  in.v = *(const uint4*)(row + c0);
  float f[8];
  float s = 0.f;
#pragma unroll
  for (int k = 0; k < 8; ++k) { f[k] = bf2f(in.s[k]); s += f[k]; }
  for (int o = 32; o; o >>= 1) s += __shfl_xor(s, o);
  const float mu = s * (1.f / 512.f);
  float q = 0.f;
#pragma unroll
  for (int k = 0; k < 8; ++k) { const float d = f[k] - mu; q += d * d; }
  for (int o = 32; o; o >>= 1) q += __shfl_xor(q, o);
  const float rs = rsqrtf(q * (1.f / 512.f) + LN_EPS);
  union { uint4 v; unsigned short s[8]; } outv;
#pragma unroll
  for (int k = 0; k < 8; ++k) {
    const float y = fmaxf((f[k] - mu) * rs * g2[c0 + k] + be2[c0 + k], 0.f);
    outv.s[k] = f2bf_bits(y);
  }
  *(uint4*)(row + c0) = outv.v;
}

// =====================================================================================
// K_j: out[b][f] = max over 32 row-blocks of pmax + b4[f]
// =====================================================================================
__global__ __launch_bounds__(256) void final_kernel(
    const float* __restrict__ pmax, const float* __restrict__ b4,
    float* __restrict__ out) {
  const int idx = blockIdx.x * 256 + threadIdx.x;
  const int b = idx >> 10, f = idx & 1023;
  float m = -1e30f;
  for (int r = 0; r < 32; ++r) m = fmaxf(m, pmax[((size_t)(b * 32 + r)) * 1024 + f]);
  out[idx] = m + b4[f];
}

// =====================================================================================
extern "C" void kernel_launch(void* const* d_in, const int* in_sizes, int n_in,
                              void* d_out, int out_size, void* d_ws, size_t ws_size,
                              hipStream_t stream) {
  const float* points = (const float*)d_in[0];
  const int* mask = (const int*)d_in[1];
  const float* w1 = (const float*)d_in[2];
  const float* g1 = (const float*)d_in[3];
  const float* be1 = (const float*)d_in[4];
  const float* w2 = (const float*)d_in[5];
  const float* b2 = (const float*)d_in[6];
  const float* w3 = (const float*)d_in[7];
  const float* g2 = (const float*)d_in[8];
  const float* be2 = (const float*)d_in[9];
  const float* w4 = (const float*)d_in[10];
  const float* b4 = (const float*)d_in[11];
  float* out = (float*)d_out;
  char* ws = (char*)d_ws;

  // workspace layout (h46 aliases h2: h2 is dead before GEMM3 writes h46)
  const size_t OFF_H46 = 0;                         // 134217728 B (bf16 131072x512)
  const size_t OFF_H2 = 0;                          //  33554432 B (bf16 131072x128)
  const size_t OFF_H3 = 134217728;                  //  67108864 B (bf16 131072x256)
  const size_t OFF_W2B = OFF_H3 + 67108864;         //     65536 B
  const size_t OFF_W3RB = OFF_W2B + 65536;          //    262144 B
  const size_t OFF_W4B = OFF_W3RB + 262144;         //   1048576 B
  const size_t OFF_PG = OFF_W4B + 1048576;          //   1048576 B (pg: 1024x256 f32)
  const size_t OFF_CVEC = OFF_PG + 1048576;         //     65536 B
  const size_t OFF_PMAX = OFF_CVEC + 65536;         //   4194304 B
  const size_t OFF_CNT = OFF_PMAX + 4194304;        //      4096 B
  const size_t OFF_NEWROW = OFF_CNT + 4096;         //    524288 B

  unsigned short* h2 = (unsigned short*)(ws + OFF_H2);
  unsigned short* h3 = (unsigned short*)(ws + OFF_H3);
  unsigned short* h46 = (unsigned short*)(ws + OFF_H46);
  unsigned short* w2b = (unsigned short*)(ws + OFF_W2B);
  unsigned short* w3Rb = (unsigned short*)(ws + OFF_W3RB);
  unsigned short* w4b = (unsigned short*)(ws + OFF_W4B);
  float* pg = (float*)(ws + OFF_PG);
  float* cvecp = (float*)(ws + OFF_CVEC);
  float* pmaxp = (float*)(ws + OFF_PMAX);
  int* cntp = (int*)(ws + OFF_CNT);
  int* newrow = (int*)(ws + OFF_NEWROW);

  // 0. visible-first compaction map per batch
  perm_kernel<<<32, 256, 0, stream>>>(mask, newrow, cntp);
  // 1. conv1 + LN1 + mask + relu -> h2 (compacted); fused weight fp32->bf16
  conv1_ln_kernel<<<32768 + 2688, 256, 0, stream>>>(points, w1, g1, be1, h2,
                                                    newrow, cntp, w2, w3, w4, w2b, w3Rb, w4b);
  // 2. h3 = h2 @ w2^T + b2, fused colmax -> pg (skip tiles: pg=b2 only)
  gemm_bt<3, 2><<<2048, 256, 0, stream>>>(h2, w2b, (void*)h3, pg, b2, cntp, 131072, 256, 128);
  // 3. gmax + cvec fused
  gmax_cvec_kernel<<<32, 256, 0, stream>>>(pg, w3, cvecp);
  // 4. h4 = h3 @ w3[:,256:]^T + cvec[b]  (skip tiles return)
  gemm_bt<1, 4><<<4096, 256, 0, stream>>>(h3, w3Rb, (void*)h46, nullptr, cvecp, cntp, 131072, 512, 256);
  // 5. LN2 + relu in place; zero only straddle rows [cnt, ceil128)
  ln2_kernel<<<32768, 256, 0, stream>>>(h46, cntp, g2, be2);
  // 6. h7 colmax -> pmax (skip tiles write 0)
  gemm_bt<2, 8><<<8192, 256, 0, stream>>>(h46, w4b, nullptr, pmaxp, nullptr, cntp, 131072, 1024, 512);
  // 7. out = max over row-blocks + b4
  final_kernel<<<128, 256, 0, stream>>>(pmaxp, b4, out);
}